// Round 11
// baseline (1243.150 us; speedup 1.0000x reference)
//
#include <hip/hip_runtime.h>

#define NB    131072
#define EPB   8      // batch elements per block
#define NTILE 6      // M-tiles: 2 tokens x 8 elems = 16 rows
#define SEQP  12     // 11 tokens + 1 pad
#define SXW   36     // sX row stride (f32)
#define SQW2  98     // sQ row stride (u32): q raw f32 prescaled -> ctx packed [0..31],
                     // k f32 [32..63], v f32 [64..95], pad
                     // FFN phase: h bf16 occupies u16 cols [0..127] (q+k slots, dead)

// ws layout (u16 units), per transformer block tb (stride WS_U16_PER_TB):
//   qkv hi @0      [6][64][8]   qkv lo @3072
//   wo  hi @6144   [2][64][8]   wo  lo @7168
//   w1  hi @8192   [8][64][8]   w1  lo @12288
//   w2  hi @16384  [4][2][64][8] w2 lo @20480
#define WS_U16_PER_TB 24576
#define WS_REQ_BYTES  (2 * WS_U16_PER_TB * 2)   // 98304 B

// log2(e)/sqrt(8): folds softmax 1/sqrt(hd) AND exp->exp2 base change into q at QKV write
#define QSCALE 0.51006972f

typedef short    bf16x8 __attribute__((ext_vector_type(8)));
typedef float    f32x4  __attribute__((ext_vector_type(4)));
typedef float    f32x8  __attribute__((ext_vector_type(8)));
typedef unsigned u32x8  __attribute__((ext_vector_type(8)));
typedef unsigned short u16;

struct Params {
  const float *x, *w_feat, *b_feat, *cls;
  const float *in_w[2], *in_b[2], *out_w[2], *out_b[2];
  const float *ln_a_g[2], *ln_a_b[2];
  const float *w1[2], *b1[2], *w2[2], *b2[2];
  const float *ln_b_g[2], *ln_b_b[2];
  const float *clf_w, *clf_b;
  float *out;
};

__device__ __forceinline__ float bf2f(u16 h){ return __uint_as_float(((unsigned)h)<<16); }
__device__ __forceinline__ u16 f2bf(float f){
  unsigned u = __float_as_uint(f);
  u += 0x7fffu + ((u>>16)&1u);          // RNE
  return (u16)(u>>16);
}
// native f32->bf16 RNE cast; compiler emits v_cvt_pk_bf16_f32 (pairs fuse to 1 op)
__device__ __forceinline__ u16 f2bf_hw(float f){
  return __builtin_bit_cast(u16, (__bf16)f);
}
// truncation split: a ~= hi + lo, residual <= 2^-16 |a|
__device__ __forceinline__ void split8t(const float* p, bf16x8& hi, bf16x8& lo){
  #pragma unroll
  for (int j = 0; j < 8; ++j) {
    float a = p[j];
    unsigned u = __float_as_uint(a);
    hi[j] = (short)(u >> 16);
    float r = a - __uint_as_float(u & 0xffff0000u);
    lo[j] = (short)(__float_as_uint(r) >> 16);
  }
}
// pack f32 -> (hi16<<16)|lo16 in one u32
__device__ __forceinline__ unsigned packsplit(float a){
  unsigned u  = __float_as_uint(a);
  unsigned uh = u & 0xffff0000u;
  float    r  = a - __uint_as_float(uh);
  return uh | (__float_as_uint(r) >> 16);
}
__device__ __forceinline__ void frag_from_packed(u32x8 p, bf16x8& hi, bf16x8& lo){
  #pragma unroll
  for (int j = 0; j < 8; ++j) { hi[j] = (short)(p[j] >> 16); lo[j] = (short)(p[j] & 0xffffu); }
}
// RNE split (weights fallback path only)
__device__ __forceinline__ void split8(const float* p, bf16x8& hi, bf16x8& lo){
  #pragma unroll
  for (int j = 0; j < 8; ++j) {
    float a = p[j];
    u16 h = f2bf(a);
    hi[j] = (short)h;
    lo[j] = (short)f2bf(a - bf2f(h));
  }
}
// split-precision MFMA: acc += A*B, A=ah+al, B=bh+bl (drops al*bl ~ 2^-17)
__device__ __forceinline__ f32x4 mfma3(bf16x8 ah, bf16x8 al, bf16x8 bh, bf16x8 bl, f32x4 acc){
  acc = __builtin_amdgcn_mfma_f32_16x16x32_bf16(ah, bl, acc, 0,0,0);
  acc = __builtin_amdgcn_mfma_f32_16x16x32_bf16(al, bh, acc, 0,0,0);
  acc = __builtin_amdgcn_mfma_f32_16x16x32_bf16(ah, bh, acc, 0,0,0);
  return acc;
}
// A exact bf16, B split: acc += A*(bh+bl)
__device__ __forceinline__ f32x4 mfma2(bf16x8 a, bf16x8 bh, bf16x8 bl, f32x4 acc){
  acc = __builtin_amdgcn_mfma_f32_16x16x32_bf16(a, bl, acc, 0,0,0);
  acc = __builtin_amdgcn_mfma_f32_16x16x32_bf16(a, bh, acc, 0,0,0);
  return acc;
}
__device__ __forceinline__ bf16x8 ld8(const u16* p){ return *reinterpret_cast<const bf16x8*>(p); }

__device__ __forceinline__ float fast_exp2(float x){
#if __has_builtin(__builtin_amdgcn_exp2f)
  return __builtin_amdgcn_exp2f(x);
#else
  return exp2f(x);
#endif
}

// GELU, tanh form rewritten as v*sigmoid with exp2 folded into the polynomial.
// res = v*e/(e+1), e = 2^(k1*v + k3*v^3); k1 = 2*0.79788456*log2e, k3 = k1*0.044715.
// Inf-safe: e=+inf -> r=0 -> res=v;  e=0 -> r=1 -> res=0.   7 VALU ops total.
__device__ __forceinline__ float gelu_fast(float v){
  float t = v * v;
  float y = v * fmaf(0.10294322f, t, 2.3022081f);
  float e = fast_exp2(y);
  float r = __builtin_amdgcn_rcpf(e + 1.f);
  return fmaf(-v, r, v);
}

// 16-lane all-reduce sum via DPP row rotate (no DS pipe; rocPRIM-standard pattern)
template<int C>
__device__ __forceinline__ float dppadd(float x){
  int t = __builtin_amdgcn_update_dpp(0, __float_as_int(x), C, 0xF, 0xF, true);
  return x + __int_as_float(t);
}
__device__ __forceinline__ float rowsum16(float x){
  x = dppadd<0x121>(x);   // row_ror:1
  x = dppadd<0x122>(x);   // row_ror:2
  x = dppadd<0x124>(x);   // row_ror:4
  x = dppadd<0x128>(x);   // row_ror:8
  return x;
}

// ---------- prep: pre-split weights into per-lane B-fragment layout ----------
__global__ void OptimusPrime_prep(Params P, u16* ws)
{
  const int tb = blockIdx.x;
  u16* b = ws + tb * WS_U16_PER_TB;
  for (int idx = threadIdx.x; idx < 12288; idx += 256) {
    float v; int hiOff, loOff;
    if (idx < 3072) {                       // qkv  [6][64][8], K=32
      int nt = idx >> 9, lane = (idx >> 3) & 63, j = idx & 7;
      v = P.in_w[tb][(nt*16 + (lane&15))*32 + (lane>>4)*8 + j];
      hiOff = idx; loOff = 3072 + idx;
    } else if (idx < 4096) {                // wo   [2][64][8], K=32
      int m = idx - 3072;
      int nt = m >> 9, lane = (m >> 3) & 63, j = m & 7;
      v = P.out_w[tb][(nt*16 + (lane&15))*32 + (lane>>4)*8 + j];
      hiOff = 6144 + m; loOff = 7168 + m;
    } else if (idx < 8192) {                // w1   [8][64][8], K=32
      int m = idx - 4096;
      int nt = m >> 9, lane = (m >> 3) & 63, j = m & 7;
      v = P.w1[tb][(nt*16 + (lane&15))*32 + (lane>>4)*8 + j];
      hiOff = 8192 + m; loOff = 12288 + m;
    } else {                                // w2   [4][2][64][8], K=128
      int m = idx - 8192;
      int kt = m >> 10, nt = (m >> 9) & 1, lane = (m >> 3) & 63, j = m & 7;
      v = P.w2[tb][(nt*16 + (lane&15))*128 + kt*32 + (lane>>4)*8 + j];
      hiOff = 16384 + m; loOff = 20480 + m;
    }
    u16 h = f2bf(v);
    b[hiOff] = h;
    b[loOff] = f2bf(v - bf2f(h));
  }
}

// MFMA 16x16x32 bf16 layouts:
//   A-frag: a[j] = A[m=lane&15][k=(lane>>4)*8+j]
//   B-frag: b[j] = B[k=(lane>>4)*8+j][n=lane&15]
//   C/D   : acc[r] = C[row=(lane>>4)*4+r][col=lane&15]
// M-tile t covers rows m in [0,16): token s = 2t + (m>>3), elem e = m&7.

// launch_bounds(256,3): LDS (3x52KB) caps at 3 blocks/CU anyway, so give the
// allocator 168 regs -> no scratch spill (r9's (256,4) spilled 61MB; benign
// but noisy). k,v stored as RAW f32: kills all bf16 unpack shifts in the
// attention inner loop (the fattest critical-path phase, ~840->~500 VALU).
// Occupancy 45->34% is a non-lever (proven r6 vs r4/r9).
template<bool WS>
__global__ __launch_bounds__(256, 3)
void OptimusPrime_kernel(Params P, const u16* __restrict__ ws)
{
  __shared__ float    sX[SEQP][EPB][SXW];   // 13824 B : residual stream (f32)
  __shared__ unsigned sQ[SEQP][EPB][SQW2];  // 37632 B : q f32/ctx packed + f32 k,v ; FFN h bf16

  const int tid  = threadIdx.x;
  const int w    = tid >> 6;
  const int lane = tid & 63;
  const int quad = lane >> 4;
  const int l16  = lane & 15;
  const int kq   = quad * 8;
  const int base = blockIdx.x * EPB;

  const int sA  = (l16 >> 3);
  const int eA  = (l16 & 7);
  const int sC  = (quad >> 1);
  const int eC0 = (quad & 1) * 4;

  // ---------- embed (float4-vectorized: 3 iterations) ----------
  for (int i = tid; i < SEQP*EPB*8; i += 256) {
    int d4 = (i & 7) << 2, e = (i >> 3) & 7, s = i >> 6;
    f32x4 v;
    if (s == 0 || s == 11) v = *reinterpret_cast<const f32x4*>(&P.cls[d4]);
    else {
      float xv = P.x[(base+e)*10 + (s-1)];
      f32x4 wv = *reinterpret_cast<const f32x4*>(&P.w_feat[(s-1)*32 + d4]);
      f32x4 bv = *reinterpret_cast<const f32x4*>(&P.b_feat[(s-1)*32 + d4]);
      #pragma unroll
      for (int j = 0; j < 4; ++j) v[j] = fmaf(xv, wv[j], bv[j]);
    }
    *reinterpret_cast<f32x4*>(&sX[s][e][d4]) = v;
  }
  __syncthreads();

  for (int tb = 0; tb < 2; ++tb) {
    const u16* wsb = WS ? (ws + tb * WS_U16_PER_TB) : nullptr;

    // ---------- QKV projection (weights streamed per-nt) ----------
    {
      for (int t = w; t < NTILE; t += 4) {
        bf16x8 ah, al; split8t(&sX[2*t + sA][eA][kq], ah, al);
        #pragma unroll
        for (int nt = 0; nt < 6; ++nt) {
          bf16x8 bh, bl;
          if (WS) {
            bh = ld8(wsb + (nt*64 + lane)*8);
            bl = ld8(wsb + 3072 + (nt*64 + lane)*8);
          } else {
            split8(P.in_w[tb] + (nt*16 + l16)*32 + kq, bh, bl);
          }
          float bias = P.in_b[tb][nt*16 + l16];
          f32x4 acc = {bias, bias, bias, bias};                   // bias folded into C-in
          acc = mfma3(ah, al, bh, bl, acc);
          #pragma unroll
          for (int r = 0; r < 4; ++r) {
            float* qrow = (float*)&sQ[2*t + sC][eC0 + r][0];
            if (nt < 2) {
              qrow[nt*16 + l16] = acc[r] * QSCALE;                // q: raw f32, prescaled
            } else if (nt < 4) {
              qrow[32 + (nt-2)*16 + l16] = acc[r];                // k: raw f32 (no cvt)
            } else {
              qrow[64 + (nt-4)*16 + l16] = acc[r];                // v: raw f32 (no cvt)
            }
          }
        }
      }
    }
    __syncthreads();

    // ---------- attention (fused score+PV; all-f32 LDS operands) ----------
    // 352 items (qi,e,hh) mapped linearly: round 2 (it>=256) lands on threads 0..95
    // only -> waves 2,3 skip it entirely via execz instead of running fully masked.
    {
      for (int it = tid; it < 352; it += 256) {
        const int qi = it >> 5;
        const int e  = (it >> 2) & 7;
        const int hh = it & 3;
        f32x8 qv = *reinterpret_cast<const f32x8*>(&sQ[qi][e][hh*8]);  // prescaled f32 q
        float l0 = 0.f, l1 = 0.f;
        float cx[8] = {0,0,0,0,0,0,0,0};
        #pragma unroll
        for (int ki = 0; ki < 11; ++ki) {
          const float* rr = (const float*)&sQ[ki][e][0];
          f32x8 kv = *reinterpret_cast<const f32x8*>(rr + 32 + hh*8);
          f32x8 vv = *reinterpret_cast<const f32x8*>(rr + 64 + hh*8);
          // two 4-deep fma chains instead of one 8-deep (halves dep latency)
          float s0 = qv[0] * kv[0];
          float s1 = qv[1] * kv[1];
          s0 = fmaf(qv[2], kv[2], s0);
          s1 = fmaf(qv[3], kv[3], s1);
          s0 = fmaf(qv[4], kv[4], s0);
          s1 = fmaf(qv[5], kv[5], s1);
          s0 = fmaf(qv[6], kv[6], s0);
          s1 = fmaf(qv[7], kv[7], s1);
          float p = fast_exp2(s0 + s1);   // q prescaled by log2e/sqrt(8): exp2 direct
          if (ki & 1) l1 += p; else l0 += p;
          #pragma unroll
          for (int j = 0; j < 8; ++j) cx[j] += p * vv[j];
        }
        float inv = __builtin_amdgcn_rcpf(l0 + l1);
        unsigned* wq = &sQ[qi][e][hh*8];
        #pragma unroll
        for (int j = 0; j < 8; ++j) wq[j] = packsplit(cx[j] * inv);   // ctx -> q slot, packed
      }
    }
    __syncthreads();

    // ---------- P3a: out-proj + LN_a (wo is small: 16 regs, keep hoisted) ----------
    {
      bf16x8 woh[2], wol[2]; float ob[2], lag[2], lab[2];
      #pragma unroll
      for (int nt = 0; nt < 2; ++nt) {
        if (WS) {
          woh[nt] = ld8(wsb + 6144 + (nt*64 + lane)*8);
          wol[nt] = ld8(wsb + 7168 + (nt*64 + lane)*8);
        } else {
          split8(P.out_w[tb] + (nt*16 + l16)*32 + kq, woh[nt], wol[nt]);
        }
        ob[nt]  = P.out_b[tb][nt*16 + l16];
        lag[nt] = P.ln_a_g[tb][nt*16 + l16]; lab[nt] = P.ln_a_b[tb][nt*16 + l16];
      }
      for (int t = w; t < NTILE; t += 4) {
        u32x8 cp = *reinterpret_cast<const u32x8*>(&sQ[2*t + sA][eA][kq]);
        bf16x8 ah, al; frag_from_packed(cp, ah, al);
        float tt[2][4];
        #pragma unroll
        for (int nt = 0; nt < 2; ++nt) {
          f32x4 acc = {ob[nt], ob[nt], ob[nt], ob[nt]};            // out-bias folded
          acc = mfma3(ah, al, woh[nt], wol[nt], acc);
          #pragma unroll
          for (int r = 0; r < 4; ++r)
            tt[nt][r] = acc[r] + sX[2*t + sC][eC0 + r][nt*16 + l16];  // + residual
        }
        #pragma unroll
        for (int r = 0; r < 4; ++r) {
          float s1 = rowsum16(tt[0][r] + tt[1][r]);
          float s2 = rowsum16(fmaf(tt[0][r], tt[0][r], tt[1][r]*tt[1][r]));
          float mu  = s1 * (1.f/32.f);
          float var = fmaxf(s2 * (1.f/32.f) - mu*mu, 0.f);
          float rs  = rsqrtf(var + 1e-5f);
          #pragma unroll
          for (int nt = 0; nt < 2; ++nt) {
            float y = (tt[nt][r] - mu)*rs*lag[nt] + lab[nt];
            sX[2*t + sC][eC0 + r][nt*16 + l16] = y;
          }
        }
      }
    }
    __builtin_amdgcn_sched_barrier(0);

    // ---------- P3b: FFN1 + GELU -> h bf16 (w1 streamed per-fi) ----------
    // h[feature f] stored as bf16 in u16 cols [0..127] of own tile rows (q+k slots, dead)
    {
      for (int t = w; t < NTILE; t += 4) {
        bf16x8 xh, xl; split8t(&sX[2*t + sA][eA][kq], xh, xl);
        #pragma unroll
        for (int fi = 0; fi < 8; ++fi) {
          bf16x8 w1h, w1l;
          if (WS) {
            w1h = ld8(wsb + 8192  + (fi*64 + lane)*8);
            w1l = ld8(wsb + 12288 + (fi*64 + lane)*8);
          } else {
            split8(P.w1[tb] + (fi*16 + l16)*32 + kq, w1h, w1l);
          }
          float b1v = P.b1[tb][fi*16 + l16];
          f32x4 acc = {b1v, b1v, b1v, b1v};                        // ffn1-bias folded
          acc = mfma3(xh, xl, w1h, w1l, acc);
          #pragma unroll
          for (int r = 0; r < 4; ++r)
            ((u16*)&sQ[2*t + sC][eC0 + r][0])[fi*16 + l16] = f2bf_hw(gelu_fast(acc[r]));
        }
      }
    }
    __builtin_amdgcn_sched_barrier(0);

    // ---------- P3c: FFN2 + residual + LN_b (w2 streamed per-kt) ----------
    {
      float b2v[2], lbg[2], lbb[2];
      #pragma unroll
      for (int nt = 0; nt < 2; ++nt) {
        b2v[nt] = P.b2[tb][nt*16 + l16];
        lbg[nt] = P.ln_b_g[tb][nt*16 + l16]; lbb[nt] = P.ln_b_b[tb][nt*16 + l16];
      }
      for (int t = w; t < NTILE; t += 4) {
        f32x4 ca0 = {b2v[0], b2v[0], b2v[0], b2v[0]};              // ffn2-bias folded
        f32x4 ca1 = {b2v[1], b2v[1], b2v[1], b2v[1]};
        #pragma unroll
        for (int kt = 0; kt < 4; ++kt) {
          bf16x8 hf = ld8((const u16*)&sQ[2*t + sA][eA][0] + kt*32 + kq);
          bf16x8 w2h0, w2l0, w2h1, w2l1;
          if (WS) {
            w2h0 = ld8(wsb + 16384 + ((kt*2 + 0)*64 + lane)*8);
            w2l0 = ld8(wsb + 20480 + ((kt*2 + 0)*64 + lane)*8);
            w2h1 = ld8(wsb + 16384 + ((kt*2 + 1)*64 + lane)*8);
            w2l1 = ld8(wsb + 20480 + ((kt*2 + 1)*64 + lane)*8);
          } else {
            split8(P.w2[tb] + (0*16 + l16)*128 + kt*32 + kq, w2h0, w2l0);
            split8(P.w2[tb] + (1*16 + l16)*128 + kt*32 + kq, w2h1, w2l1);
          }
          ca0 = mfma2(hf, w2h0, w2l0, ca0);
          ca1 = mfma2(hf, w2h1, w2l1, ca1);
        }
        float tt[2][4];
        #pragma unroll
        for (int nt = 0; nt < 2; ++nt) {
          f32x4 ca = nt ? ca1 : ca0;
          #pragma unroll
          for (int r = 0; r < 4; ++r)
            tt[nt][r] = ca[r] + sX[2*t + sC][eC0 + r][nt*16 + l16];  // + residual
        }
        #pragma unroll
        for (int r = 0; r < 4; ++r) {
          float s1 = rowsum16(tt[0][r] + tt[1][r]);
          float s2 = rowsum16(fmaf(tt[0][r], tt[0][r], tt[1][r]*tt[1][r]));
          float mu  = s1 * (1.f/32.f);
          float var = fmaxf(s2 * (1.f/32.f) - mu*mu, 0.f);
          float rs  = rsqrtf(var + 1e-5f);
          #pragma unroll
          for (int nt = 0; nt < 2; ++nt) {
            float y = (tt[nt][r] - mu)*rs*lbg[nt] + lbb[nt];
            sX[2*t + sC][eC0 + r][nt*16 + l16] = y;
          }
        }
      }
    }
    __syncthreads();
  }

  // ---------- classifier: out[b] = sX[0][e][:] . clf_w + clf_b ----------
  if (w == 0) {
    int e = lane >> 3, dq = lane & 7;
    float p = 0.f;
    #pragma unroll
    for (int j = 0; j < 4; ++j)
      p += sX[0][e][dq*4 + j] * P.clf_w[dq*4 + j];
    p += __shfl_xor(p, 1);
    p += __shfl_xor(p, 2);
    p += __shfl_xor(p, 4);
    if (dq == 0)
      P.out[base + e] = p + P.clf_b[0];
  }
}

extern "C" void kernel_launch(void* const* d_in, const int* in_sizes, int n_in,
                              void* d_out, int out_size, void* d_ws, size_t ws_size,
                              hipStream_t stream)
{
  Params P;
  P.x        = (const float*)d_in[0];
  P.w_feat   = (const float*)d_in[1];
  P.b_feat   = (const float*)d_in[2];
  P.cls      = (const float*)d_in[3];
  P.in_w[0]  = (const float*)d_in[4];   P.in_b[0]  = (const float*)d_in[5];
  P.out_w[0] = (const float*)d_in[6];   P.out_b[0] = (const float*)d_in[7];
  P.ln_a_g[0]= (const float*)d_in[8];   P.ln_a_b[0]= (const float*)d_in[9];
  P.w1[0]    = (const float*)d_in[10];  P.b1[0]    = (const float*)d_in[11];
  P.w2[0]    = (const float*)d_in[12];  P.b2[0]    = (const float*)d_in[13];
  P.ln_b_g[0]= (const float*)d_in[14];  P.ln_b_b[0]= (const float*)d_in[15];
  P.in_w[1]  = (const float*)d_in[16];  P.in_b[1]  = (const float*)d_in[17];
  P.out_w[1] = (const float*)d_in[18];  P.out_b[1] = (const float*)d_in[19];
  P.ln_a_g[1]= (const float*)d_in[20];  P.ln_a_b[1]= (const float*)d_in[21];
  P.w1[1]    = (const float*)d_in[22];  P.b1[1]    = (const float*)d_in[23];
  P.w2[1]    = (const float*)d_in[24];  P.b2[1]    = (const float*)d_in[25];
  P.ln_b_g[1]= (const float*)d_in[26];  P.ln_b_b[1]= (const float*)d_in[27];
  P.clf_w    = (const float*)d_in[28];  P.clf_b    = (const float*)d_in[29];
  P.out      = (float*)d_out;

  dim3 grid(NB / EPB), block(256);
  if (ws_size >= (size_t)WS_REQ_BYTES) {
    u16* ws = (u16*)d_ws;
    hipLaunchKernelGGL(OptimusPrime_prep, dim3(2), dim3(256), 0, stream, P, ws);
    hipLaunchKernelGGL(OptimusPrime_kernel<true>, grid, block, 0, stream, P, (const u16*)ws);
  } else {
    hipLaunchKernelGGL(OptimusPrime_kernel<false>, grid, block, 0, stream, P, (const u16*)nullptr);
  }
}

// Round 13
// 839.863 us; speedup vs baseline: 1.4802x; 1.4802x over previous
//
#include <hip/hip_runtime.h>

#define NB    131072
#define EPB   8      // batch elements per block
#define NTILE 6      // M-tiles: 2 tokens x 8 elems = 16 rows
#define SEQP  12     // 11 tokens + 1 pad
#define SXW   36     // sX row stride (f32)
#define SQW2  66     // sQ row stride (u32): q raw f32 prescaled -> ctx packed [0..31],
                     // k f16 [u16 64..95], v f16 [u16 96..127], pad
                     // FFN phase: h bf16 occupies u16 cols [0..127] of the same row

// ws layout (u16 units), per transformer block tb (stride WS_U16_PER_TB):
//   qkv hi @0      [6][64][8]   qkv lo @3072   (q rows nt<2 pre-scaled by QSCALE)
//   wo  hi @6144   [2][64][8]   wo  lo @7168
//   w1  hi @8192   [8][64][8]   w1  lo @12288
//   w2  hi @16384  [4][2][64][8] w2 lo @20480
#define WS_U16_PER_TB 24576
#define WS_REQ_BYTES  (2 * WS_U16_PER_TB * 2)   // 98304 B

// log2(e)/sqrt(8): folds softmax 1/sqrt(hd) AND exp->exp2 base change into q
#define QSCALE 0.51006972f

typedef short    bf16x8 __attribute__((ext_vector_type(8)));
typedef __fp16   h16x8  __attribute__((ext_vector_type(8)));
typedef float    f32x4  __attribute__((ext_vector_type(4)));
typedef float    f32x8  __attribute__((ext_vector_type(8)));
typedef unsigned u32x8  __attribute__((ext_vector_type(8)));
typedef unsigned short u16;

struct Params {
  const float *x, *w_feat, *b_feat, *cls;
  const float *in_w[2], *in_b[2], *out_w[2], *out_b[2];
  const float *ln_a_g[2], *ln_a_b[2];
  const float *w1[2], *b1[2], *w2[2], *b2[2];
  const float *ln_b_g[2], *ln_b_b[2];
  const float *clf_w, *clf_b;
  float *out;
};

__device__ __forceinline__ float bf2f(u16 h){ return __uint_as_float(((unsigned)h)<<16); }
__device__ __forceinline__ u16 f2bf(float f){
  unsigned u = __float_as_uint(f);
  u += 0x7fffu + ((u>>16)&1u);          // RNE
  return (u16)(u>>16);
}
// native f32->bf16 RNE cast; compiler emits v_cvt_pk_bf16_f32 (pairs fuse to 1 op)
__device__ __forceinline__ u16 f2bf_hw(float f){
  return __builtin_bit_cast(u16, (__bf16)f);
}
__device__ __forceinline__ u16 f2h_hw(float f){
  return __builtin_bit_cast(u16, (__fp16)f);   // v_cvt_f16_f32, RNE
}
// truncation split: a ~= hi + lo, residual <= 2^-16 |a|
__device__ __forceinline__ void split8t(const float* p, bf16x8& hi, bf16x8& lo){
  #pragma unroll
  for (int j = 0; j < 8; ++j) {
    float a = p[j];
    unsigned u = __float_as_uint(a);
    hi[j] = (short)(u >> 16);
    float r = a - __uint_as_float(u & 0xffff0000u);
    lo[j] = (short)(__float_as_uint(r) >> 16);
  }
}
// pack f32 -> (hi16<<16)|lo16 in one u32
__device__ __forceinline__ unsigned packsplit(float a){
  unsigned u  = __float_as_uint(a);
  unsigned uh = u & 0xffff0000u;
  float    r  = a - __uint_as_float(uh);
  return uh | (__float_as_uint(r) >> 16);
}
__device__ __forceinline__ void frag_from_packed(u32x8 p, bf16x8& hi, bf16x8& lo){
  #pragma unroll
  for (int j = 0; j < 8; ++j) { hi[j] = (short)(p[j] >> 16); lo[j] = (short)(p[j] & 0xffffu); }
}
// RNE split (weights fallback path only)
__device__ __forceinline__ void split8(const float* p, bf16x8& hi, bf16x8& lo){
  #pragma unroll
  for (int j = 0; j < 8; ++j) {
    float a = p[j];
    u16 h = f2bf(a);
    hi[j] = (short)h;
    lo[j] = (short)f2bf(a - bf2f(h));
  }
}
// split-precision MFMA: acc += A*B, A=ah+al, B=bh+bl (drops al*bl ~ 2^-17)
__device__ __forceinline__ f32x4 mfma3(bf16x8 ah, bf16x8 al, bf16x8 bh, bf16x8 bl, f32x4 acc){
  acc = __builtin_amdgcn_mfma_f32_16x16x32_bf16(ah, bl, acc, 0,0,0);
  acc = __builtin_amdgcn_mfma_f32_16x16x32_bf16(al, bh, acc, 0,0,0);
  acc = __builtin_amdgcn_mfma_f32_16x16x32_bf16(ah, bh, acc, 0,0,0);
  return acc;
}
// A exact bf16, B split: acc += A*(bh+bl)
__device__ __forceinline__ f32x4 mfma2(bf16x8 a, bf16x8 bh, bf16x8 bl, f32x4 acc){
  acc = __builtin_amdgcn_mfma_f32_16x16x32_bf16(a, bl, acc, 0,0,0);
  acc = __builtin_amdgcn_mfma_f32_16x16x32_bf16(a, bh, acc, 0,0,0);
  return acc;
}
__device__ __forceinline__ bf16x8 ld8(const u16* p){ return *reinterpret_cast<const bf16x8*>(p); }

__device__ __forceinline__ float fast_exp2(float x){
#if __has_builtin(__builtin_amdgcn_exp2f)
  return __builtin_amdgcn_exp2f(x);
#else
  return exp2f(x);
#endif
}

// GELU, tanh form rewritten as v*sigmoid with exp2 folded into the polynomial.
// res = v*e/(e+1), e = 2^(k1*v + k3*v^3); k1 = 2*0.79788456*log2e, k3 = k1*0.044715.
// Inf-safe: e=+inf -> r=0 -> res=v;  e=0 -> r=1 -> res=0.   7 VALU ops total.
__device__ __forceinline__ float gelu_fast(float v){
  float t = v * v;
  float y = v * fmaf(0.10294322f, t, 2.3022081f);
  float e = fast_exp2(y);
  float r = __builtin_amdgcn_rcpf(e + 1.f);
  return fmaf(-v, r, v);
}

// 16-lane all-reduce sum via DPP row rotate (no DS pipe; rocPRIM-standard pattern)
template<int C>
__device__ __forceinline__ float dppadd(float x){
  int t = __builtin_amdgcn_update_dpp(0, __float_as_int(x), C, 0xF, 0xF, true);
  return x + __int_as_float(t);
}
__device__ __forceinline__ float rowsum16(float x){
  x = dppadd<0x121>(x);   // row_ror:1
  x = dppadd<0x122>(x);   // row_ror:2
  x = dppadd<0x124>(x);   // row_ror:4
  x = dppadd<0x128>(x);   // row_ror:8
  return x;
}

// ---------- prep: pre-split weights into per-lane B-fragment layout ----------
__global__ void OptimusPrime_prep(Params P, u16* ws)
{
  const int tb = blockIdx.x;
  u16* b = ws + tb * WS_U16_PER_TB;
  for (int idx = threadIdx.x; idx < 12288; idx += 256) {
    float v; int hiOff, loOff;
    if (idx < 3072) {                       // qkv  [6][64][8], K=32
      int nt = idx >> 9, lane = (idx >> 3) & 63, j = idx & 7;
      v = P.in_w[tb][(nt*16 + (lane&15))*32 + (lane>>4)*8 + j];
      if (nt < 2) v *= QSCALE;              // fold softmax scale + exp2 base into q weights
      hiOff = idx; loOff = 3072 + idx;
    } else if (idx < 4096) {                // wo   [2][64][8], K=32
      int m = idx - 3072;
      int nt = m >> 9, lane = (m >> 3) & 63, j = m & 7;
      v = P.out_w[tb][(nt*16 + (lane&15))*32 + (lane>>4)*8 + j];
      hiOff = 6144 + m; loOff = 7168 + m;
    } else if (idx < 8192) {                // w1   [8][64][8], K=32
      int m = idx - 4096;
      int nt = m >> 9, lane = (m >> 3) & 63, j = m & 7;
      v = P.w1[tb][(nt*16 + (lane&15))*32 + (lane>>4)*8 + j];
      hiOff = 8192 + m; loOff = 12288 + m;
    } else {                                // w2   [4][2][64][8], K=128
      int m = idx - 8192;
      int kt = m >> 10, nt = (m >> 9) & 1, lane = (m >> 3) & 63, j = m & 7;
      v = P.w2[tb][(nt*16 + (lane&15))*128 + kt*32 + (lane>>4)*8 + j];
      hiOff = 16384 + m; loOff = 20480 + m;
    }
    u16 h = f2bf(v);
    b[hiOff] = h;
    b[loOff] = f2bf(v - bf2f(h));
  }
}

// MFMA 16x16x32 bf16 layouts:
//   A-frag: a[j] = A[m=lane&15][k=(lane>>4)*8+j]
//   B-frag: b[j] = B[k=(lane>>4)*8+j][n=lane&15]
//   C/D   : acc[r] = C[row=(lane>>4)*4+r][col=lane&15]
// M-tile t covers rows m in [0,16): token s = 2t + (m>>3), elem e = m&7.

// launch_bounds(256,4): 4 waves/SIMD -> 4 blocks/CU. k,v stored as f16
// (RNE, strictly more precise than bf16 for O(1) values); attention fmas
// consume the half operands via v_fma_mix_f32 -> no unpack shifts.
// 16B/lane LDS loads only (r11 lesson: 32B operands serialize the loop).
template<bool WS>
__global__ __launch_bounds__(256, 4)
void OptimusPrime_kernel(Params P, const u16* __restrict__ ws)
{
  __shared__ float    sX[SEQP][EPB][SXW];   // 13824 B : residual stream (f32)
  __shared__ unsigned sQ[SEQP][EPB][SQW2];  // 25344 B : q f32/ctx packed + f16 k,v ; FFN h bf16

  const int tid  = threadIdx.x;
  const int w    = tid >> 6;
  const int lane = tid & 63;
  const int quad = lane >> 4;
  const int l16  = lane & 15;
  const int kq   = quad * 8;
  const int base = blockIdx.x * EPB;

  const int sA  = (l16 >> 3);
  const int eA  = (l16 & 7);
  const int sC  = (quad >> 1);
  const int eC0 = (quad & 1) * 4;

  // ---------- embed (float4-vectorized: 3 iterations) ----------
  for (int i = tid; i < SEQP*EPB*8; i += 256) {
    int d4 = (i & 7) << 2, e = (i >> 3) & 7, s = i >> 6;
    f32x4 v;
    if (s == 0 || s == 11) v = *reinterpret_cast<const f32x4*>(&P.cls[d4]);
    else {
      float xv = P.x[(base+e)*10 + (s-1)];
      f32x4 wv = *reinterpret_cast<const f32x4*>(&P.w_feat[(s-1)*32 + d4]);
      f32x4 bv = *reinterpret_cast<const f32x4*>(&P.b_feat[(s-1)*32 + d4]);
      #pragma unroll
      for (int j = 0; j < 4; ++j) v[j] = fmaf(xv, wv[j], bv[j]);
    }
    *reinterpret_cast<f32x4*>(&sX[s][e][d4]) = v;
  }
  __syncthreads();

  for (int tb = 0; tb < 2; ++tb) {
    const u16* wsb = WS ? (ws + tb * WS_U16_PER_TB) : nullptr;

    // ---------- QKV projection (weights streamed per-nt) ----------
    {
      for (int t = w; t < NTILE; t += 4) {
        bf16x8 ah, al; split8t(&sX[2*t + sA][eA][kq], ah, al);
        #pragma unroll
        for (int nt = 0; nt < 6; ++nt) {
          bf16x8 bh, bl;
          if (WS) {
            bh = ld8(wsb + (nt*64 + lane)*8);
            bl = ld8(wsb + 3072 + (nt*64 + lane)*8);
          } else {
            split8(P.in_w[tb] + (nt*16 + l16)*32 + kq, bh, bl);
          }
          float bias = P.in_b[tb][nt*16 + l16];
          if (nt < 2) bias *= QSCALE;       // q bias carries the folded scale
          f32x4 acc = {bias, bias, bias, bias};                   // bias folded into C-in
          acc = mfma3(ah, al, bh, bl, acc);
          #pragma unroll
          for (int r = 0; r < 4; ++r) {
            float* qrow = (float*)&sQ[2*t + sC][eC0 + r][0];
            if (nt < 2) {
              // WS path: weights pre-scaled; fallback: scale here
              qrow[nt*16 + l16] = WS ? acc[r] : acc[r] * QSCALE;  // q: raw f32, prescaled
            } else if (nt < 4) {
              ((u16*)qrow)[64 + (nt-2)*16 + l16] = f2h_hw(acc[r]);   // k f16 (HW cvt)
            } else {
              ((u16*)qrow)[96 + (nt-4)*16 + l16] = f2h_hw(acc[r]);   // v f16 (HW cvt)
            }
          }
        }
      }
    }
    __syncthreads();

    // ---------- attention (fused score+PV; f16 k/v via fma_mix; 2-chain dot) ----------
    // 352 items (qi,e,hh) mapped linearly: round 2 (it>=256) lands on threads 0..95
    // only -> waves 2,3 skip it entirely via execz instead of running fully masked.
    {
      for (int it = tid; it < 352; it += 256) {
        const int qi = it >> 5;
        const int e  = (it >> 2) & 7;
        const int hh = it & 3;
        f32x8 qv = *reinterpret_cast<const f32x8*>(&sQ[qi][e][hh*8]);  // prescaled f32 q
        float l0 = 0.f, l1 = 0.f;
        float cx[8] = {0,0,0,0,0,0,0,0};
        #pragma unroll
        for (int ki = 0; ki < 11; ++ki) {
          const u16* rr = (const u16*)&sQ[ki][e][0];
          h16x8 kv = *reinterpret_cast<const h16x8*>(rr + 64 + hh*8);  // 16B load
          h16x8 vv = *reinterpret_cast<const h16x8*>(rr + 96 + hh*8);  // 16B load
          // two 4-deep fma chains; f16 operand consumed via v_fma_mix_f32
          float s0 = qv[0] * (float)kv[0];
          float s1 = qv[1] * (float)kv[1];
          s0 = fmaf(qv[2], (float)kv[2], s0);
          s1 = fmaf(qv[3], (float)kv[3], s1);
          s0 = fmaf(qv[4], (float)kv[4], s0);
          s1 = fmaf(qv[5], (float)kv[5], s1);
          s0 = fmaf(qv[6], (float)kv[6], s0);
          s1 = fmaf(qv[7], (float)kv[7], s1);
          float p = fast_exp2(s0 + s1);   // q prescaled by log2e/sqrt(8): exp2 direct
          if (ki & 1) l1 += p; else l0 += p;
          #pragma unroll
          for (int j = 0; j < 8; ++j) cx[j] = fmaf(p, (float)vv[j], cx[j]);
        }
        float inv = __builtin_amdgcn_rcpf(l0 + l1);
        unsigned* wq = &sQ[qi][e][hh*8];
        #pragma unroll
        for (int j = 0; j < 8; ++j) wq[j] = packsplit(cx[j] * inv);   // ctx -> q slot, packed
      }
    }
    __syncthreads();

    // ---------- P3a: out-proj + LN_a (wo is small: 16 regs, keep hoisted) ----------
    {
      bf16x8 woh[2], wol[2]; float ob[2], lag[2], lab[2];
      #pragma unroll
      for (int nt = 0; nt < 2; ++nt) {
        if (WS) {
          woh[nt] = ld8(wsb + 6144 + (nt*64 + lane)*8);
          wol[nt] = ld8(wsb + 7168 + (nt*64 + lane)*8);
        } else {
          split8(P.out_w[tb] + (nt*16 + l16)*32 + kq, woh[nt], wol[nt]);
        }
        ob[nt]  = P.out_b[tb][nt*16 + l16];
        lag[nt] = P.ln_a_g[tb][nt*16 + l16]; lab[nt] = P.ln_a_b[tb][nt*16 + l16];
      }
      for (int t = w; t < NTILE; t += 4) {
        u32x8 cp = *reinterpret_cast<const u32x8*>(&sQ[2*t + sA][eA][kq]);
        bf16x8 ah, al; frag_from_packed(cp, ah, al);
        float tt[2][4];
        #pragma unroll
        for (int nt = 0; nt < 2; ++nt) {
          f32x4 acc = {ob[nt], ob[nt], ob[nt], ob[nt]};            // out-bias folded
          acc = mfma3(ah, al, woh[nt], wol[nt], acc);
          #pragma unroll
          for (int r = 0; r < 4; ++r)
            tt[nt][r] = acc[r] + sX[2*t + sC][eC0 + r][nt*16 + l16];  // + residual
        }
        #pragma unroll
        for (int r = 0; r < 4; ++r) {
          float s1 = rowsum16(tt[0][r] + tt[1][r]);
          float s2 = rowsum16(fmaf(tt[0][r], tt[0][r], tt[1][r]*tt[1][r]));
          float mu  = s1 * (1.f/32.f);
          float var = fmaxf(s2 * (1.f/32.f) - mu*mu, 0.f);
          float rs  = rsqrtf(var + 1e-5f);
          #pragma unroll
          for (int nt = 0; nt < 2; ++nt) {
            float y = (tt[nt][r] - mu)*rs*lag[nt] + lab[nt];
            sX[2*t + sC][eC0 + r][nt*16 + l16] = y;
          }
        }
      }
    }
    __builtin_amdgcn_sched_barrier(0);

    // ---------- P3b: FFN1 + GELU -> h bf16 (w1 streamed per-fi) ----------
    // h[feature f] stored as bf16 in u16 cols [0..127] of own tile rows (overwrites dead ctx/k/v)
    {
      for (int t = w; t < NTILE; t += 4) {
        bf16x8 xh, xl; split8t(&sX[2*t + sA][eA][kq], xh, xl);
        #pragma unroll
        for (int fi = 0; fi < 8; ++fi) {
          bf16x8 w1h, w1l;
          if (WS) {
            w1h = ld8(wsb + 8192  + (fi*64 + lane)*8);
            w1l = ld8(wsb + 12288 + (fi*64 + lane)*8);
          } else {
            split8(P.w1[tb] + (fi*16 + l16)*32 + kq, w1h, w1l);
          }
          float b1v = P.b1[tb][fi*16 + l16];
          f32x4 acc = {b1v, b1v, b1v, b1v};                        // ffn1-bias folded
          acc = mfma3(xh, xl, w1h, w1l, acc);
          #pragma unroll
          for (int r = 0; r < 4; ++r)
            ((u16*)&sQ[2*t + sC][eC0 + r][0])[fi*16 + l16] = f2bf_hw(gelu_fast(acc[r]));
        }
      }
    }
    __builtin_amdgcn_sched_barrier(0);

    // ---------- P3c: FFN2 + residual + LN_b (w2 streamed per-kt) ----------
    {
      float b2v[2], lbg[2], lbb[2];
      #pragma unroll
      for (int nt = 0; nt < 2; ++nt) {
        b2v[nt] = P.b2[tb][nt*16 + l16];
        lbg[nt] = P.ln_b_g[tb][nt*16 + l16]; lbb[nt] = P.ln_b_b[tb][nt*16 + l16];
      }
      for (int t = w; t < NTILE; t += 4) {
        f32x4 ca0 = {b2v[0], b2v[0], b2v[0], b2v[0]};              // ffn2-bias folded
        f32x4 ca1 = {b2v[1], b2v[1], b2v[1], b2v[1]};
        #pragma unroll
        for (int kt = 0; kt < 4; ++kt) {
          bf16x8 hf = ld8((const u16*)&sQ[2*t + sA][eA][0] + kt*32 + kq);
          bf16x8 w2h0, w2l0, w2h1, w2l1;
          if (WS) {
            w2h0 = ld8(wsb + 16384 + ((kt*2 + 0)*64 + lane)*8);
            w2l0 = ld8(wsb + 20480 + ((kt*2 + 0)*64 + lane)*8);
            w2h1 = ld8(wsb + 16384 + ((kt*2 + 1)*64 + lane)*8);
            w2l1 = ld8(wsb + 20480 + ((kt*2 + 1)*64 + lane)*8);
          } else {
            split8(P.w2[tb] + (0*16 + l16)*128 + kt*32 + kq, w2h0, w2l0);
            split8(P.w2[tb] + (1*16 + l16)*128 + kt*32 + kq, w2h1, w2l1);
          }
          ca0 = mfma2(hf, w2h0, w2l0, ca0);
          ca1 = mfma2(hf, w2h1, w2l1, ca1);
        }
        float tt[2][4];
        #pragma unroll
        for (int nt = 0; nt < 2; ++nt) {
          f32x4 ca = nt ? ca1 : ca0;
          #pragma unroll
          for (int r = 0; r < 4; ++r)
            tt[nt][r] = ca[r] + sX[2*t + sC][eC0 + r][nt*16 + l16];  // + residual
        }
        #pragma unroll
        for (int r = 0; r < 4; ++r) {
          float s1 = rowsum16(tt[0][r] + tt[1][r]);
          float s2 = rowsum16(fmaf(tt[0][r], tt[0][r], tt[1][r]*tt[1][r]));
          float mu  = s1 * (1.f/32.f);
          float var = fmaxf(s2 * (1.f/32.f) - mu*mu, 0.f);
          float rs  = rsqrtf(var + 1e-5f);
          #pragma unroll
          for (int nt = 0; nt < 2; ++nt) {
            float y = (tt[nt][r] - mu)*rs*lbg[nt] + lbb[nt];
            sX[2*t + sC][eC0 + r][nt*16 + l16] = y;
          }
        }
      }
    }
    __syncthreads();
  }

  // ---------- classifier: out[b] = sX[0][e][:] . clf_w + clf_b ----------
  if (w == 0) {
    int e = lane >> 3, dq = lane & 7;
    float p = 0.f;
    #pragma unroll
    for (int j = 0; j < 4; ++j)
      p += sX[0][e][dq*4 + j] * P.clf_w[dq*4 + j];
    p += __shfl_xor(p, 1);
    p += __shfl_xor(p, 2);
    p += __shfl_xor(p, 4);
    if (dq == 0)
      P.out[base + e] = p + P.clf_b[0];
  }
}

extern "C" void kernel_launch(void* const* d_in, const int* in_sizes, int n_in,
                              void* d_out, int out_size, void* d_ws, size_t ws_size,
                              hipStream_t stream)
{
  Params P;
  P.x        = (const float*)d_in[0];
  P.w_feat   = (const float*)d_in[1];
  P.b_feat   = (const float*)d_in[2];
  P.cls      = (const float*)d_in[3];
  P.in_w[0]  = (const float*)d_in[4];   P.in_b[0]  = (const float*)d_in[5];
  P.out_w[0] = (const float*)d_in[6];   P.out_b[0] = (const float*)d_in[7];
  P.ln_a_g[0]= (const float*)d_in[8];   P.ln_a_b[0]= (const float*)d_in[9];
  P.w1[0]    = (const float*)d_in[10];  P.b1[0]    = (const float*)d_in[11];
  P.w2[0]    = (const float*)d_in[12];  P.b2[0]    = (const float*)d_in[13];
  P.ln_b_g[0]= (const float*)d_in[14];  P.ln_b_b[0]= (const float*)d_in[15];
  P.in_w[1]  = (const float*)d_in[16];  P.in_b[1]  = (const float*)d_in[17];
  P.out_w[1] = (const float*)d_in[18];  P.out_b[1] = (const float*)d_in[19];
  P.ln_a_g[1]= (const float*)d_in[20];  P.ln_a_b[1]= (const float*)d_in[21];
  P.w1[1]    = (const float*)d_in[22];  P.b1[1]    = (const float*)d_in[23];
  P.w2[1]    = (const float*)d_in[24];  P.b2[1]    = (const float*)d_in[25];
  P.ln_b_g[1]= (const float*)d_in[26];  P.ln_b_b[1]= (const float*)d_in[27];
  P.clf_w    = (const float*)d_in[28];  P.clf_b    = (const float*)d_in[29];
  P.out      = (float*)d_out;

  dim3 grid(NB / EPB), block(256);
  if (ws_size >= (size_t)WS_REQ_BYTES) {
    u16* ws = (u16*)d_ws;
    hipLaunchKernelGGL(OptimusPrime_prep, dim3(2), dim3(256), 0, stream, P, ws);
    hipLaunchKernelGGL(OptimusPrime_kernel<true>, grid, block, 0, stream, P, (const u16*)ws);
  } else {
    hipLaunchKernelGGL(OptimusPrime_kernel<false>, grid, block, 0, stream, P, (const u16*)nullptr);
  }
}